// Round 4
// baseline (663.565 us; speedup 1.0000x reference)
//
#include <hip/hip_runtime.h>
#include <hip/hip_bf16.h>
#include <cstdint>
#include <cstddef>

#define NROWS 32768
#define DDIM  64
#define KDIM  8192
#define CHUNK 256                 // k per block / coarse table granularity
#define NCHUNK (KDIM / CHUNK)     // 32
#define DELTA 1.0f                // prune margin (>> 2x worst bf16 score error)
#define WLCAP 262144

typedef float  f32x4 __attribute__((ext_vector_type(4)));
typedef short  s16x8 __attribute__((ext_vector_type(8)));
typedef unsigned long long u64;

// monotonic fp32 <-> u32 order-preserving map
__device__ __forceinline__ uint32_t fmono(float f) {
    uint32_t u = __float_as_uint(f);
    return (u & 0x80000000u) ? ~u : (u | 0x80000000u);
}
__device__ __forceinline__ float funmono(uint32_t m) {
    uint32_t u = (m & 0x80000000u) ? (m & 0x7fffffffu) : ~m;
    return __uint_as_float(u);
}

// ================= fast path (bf16 MFMA prune + fp32 rescore) =================

// prep: wt[k][d] fp32, wtb[k][d] bf16, wsq[k] = sum_d w[d][k]^2 (fp32 exact)
__global__ void vq_prep_w(const float* __restrict__ w,
                          float* __restrict__ wt,
                          ushort* __restrict__ wtb,
                          float* __restrict__ wsq) {
    int k = blockIdx.x * blockDim.x + threadIdx.x;
    if (k >= KDIM) return;
    float s = 0.f;
#pragma unroll
    for (int d = 0; d < DDIM; ++d) {
        float v = w[(size_t)d * KDIM + k];      // coalesced across lanes
        wt[(size_t)k * DDIM + d] = v;
        __hip_bfloat16 hb = __float2bfloat16(v);
        wtb[(size_t)k * DDIM + d] = *(ushort*)&hb;
        s = fmaf(v, v, s);
    }
    wsq[k] = s;
}

// prep: x -> bf16
__global__ void vq_prep_x(const float* __restrict__ x, ushort* __restrict__ xb) {
    int i = blockIdx.x * blockDim.x + threadIdx.x;   // one float4 per thread
    if (i >= NROWS * DDIM / 4) return;
    float4 v = ((const float4*)x)[i];
    ushort4 o;
    __hip_bfloat16 h;
    h = __float2bfloat16(v.x); o.x = *(ushort*)&h;
    h = __float2bfloat16(v.y); o.y = *(ushort*)&h;
    h = __float2bfloat16(v.z); o.z = *(ushort*)&h;
    h = __float2bfloat16(v.w); o.w = *(ushort*)&h;
    ((ushort4*)xb)[i] = o;
}

__global__ void vq_init2(u64* __restrict__ keys, uint32_t* __restrict__ cnt) {
    int i = blockIdx.x * blockDim.x + threadIdx.x;
    if (i < NROWS) keys[i] = ~0ull;
    if (i == 0) *cnt = 0u;
}

// pass A: bf16 MFMA scores, per-(row, 64k-subchunk) mins -> compact tables.
// Block: 64 rows x 256 k; wave w handles 64 k. Wave tile 64x64 = 4x4 MFMA frags.
__global__ void __launch_bounds__(256)
vq_scoreA(const ushort* __restrict__ xb, const ushort* __restrict__ wb,
          const float* __restrict__ wsq,
          u64* __restrict__ lmin, uint32_t* __restrict__ ldelta) {
    __shared__ u64 lred[64][4];

    const int bid   = blockIdx.x;
    const int cidx  = bid & (NCHUNK - 1);
    const int rbase = (bid >> 5) * 64;
    const int kbase = cidx * CHUNK;
    const int t = threadIdx.x, wv = t >> 6, lane = t & 63;
    const int l15 = lane & 15, l4 = lane >> 4;
    const int kw = kbase + wv * 64;

    // B fragments: codeword (kw+ct*16+l15), contraction elems (l4*8 .. +8) per half h
    s16x8 bfrag[4][2];
#pragma unroll
    for (int ct = 0; ct < 4; ++ct)
#pragma unroll
        for (int h = 0; h < 2; ++h)
            bfrag[ct][h] = *(const s16x8*)&wb[(size_t)(kw + ct * 16 + l15) * DDIM + h * 32 + l4 * 8];

    f32x4 acc[4][4];
#pragma unroll
    for (int rt = 0; rt < 4; ++rt)
#pragma unroll
        for (int ct = 0; ct < 4; ++ct) acc[rt][ct] = (f32x4)(0.f);

#pragma unroll
    for (int rt = 0; rt < 4; ++rt) {
        const size_t rb = (size_t)(rbase + rt * 16 + l15) * DDIM + l4 * 8;
        s16x8 a0 = *(const s16x8*)&xb[rb];
        s16x8 a1 = *(const s16x8*)&xb[rb + 32];
#pragma unroll
        for (int ct = 0; ct < 4; ++ct) {
            acc[rt][ct] = __builtin_amdgcn_mfma_f32_16x16x32_bf16(a0, bfrag[ct][0], acc[rt][ct], 0, 0, 0);
            acc[rt][ct] = __builtin_amdgcn_mfma_f32_16x16x32_bf16(a1, bfrag[ct][1], acc[rt][ct], 0, 0, 0);
        }
    }

    float wq[4];
#pragma unroll
    for (int ct = 0; ct < 4; ++ct) wq[ct] = wsq[kw + ct * 16 + l15];

    // C/D layout (verified): col = lane&15, row = (lane>>4)*4 + reg
#pragma unroll
    for (int rt = 0; rt < 4; ++rt) {
#pragma unroll
        for (int i = 0; i < 4; ++i) {
            u64 best = ~0ull;
#pragma unroll
            for (int ct = 0; ct < 4; ++ct) {
                float sc = fmaf(-2.f, acc[rt][ct][i], wq[ct]);
                u64 key = ((u64)fmono(sc) << 32) | (unsigned)(kw + ct * 16 + l15);
                best = (key < best) ? key : best;
            }
            u64 o;
            o = __shfl_xor(best, 1); best = (o < best) ? o : best;
            o = __shfl_xor(best, 2); best = (o < best) ? o : best;
            o = __shfl_xor(best, 4); best = (o < best) ? o : best;
            o = __shfl_xor(best, 8); best = (o < best) ? o : best;
            if (l15 == 0) lred[rt * 16 + l4 * 4 + i][wv] = best;
        }
    }
    __syncthreads();

    if (t < 64) {
        u64 s0 = lred[t][0], s1 = lred[t][1], s2 = lred[t][2], s3 = lred[t][3];
        u64 mk = s0;
        mk = (s1 < mk) ? s1 : mk;
        mk = (s2 < mk) ? s2 : mk;
        mk = (s3 < mk) ? s3 : mk;
        float cf = funmono((uint32_t)(mk >> 32));
        uint32_t dpack = 0;
        u64 subs[4] = {s0, s1, s2, s3};
#pragma unroll
        for (int w4 = 0; w4 < 4; ++w4) {
            float sf = funmono((uint32_t)(subs[w4] >> 32));
            int q = (int)((sf - cf) * 4.0f);          // floor -> lower bound
            q = (q < 0) ? 0 : ((q > 255) ? 255 : q);
            dpack |= (uint32_t)q << (8 * w4);
        }
        size_t o = (size_t)(rbase + t) * NCHUNK + cidx;
        lmin[o]   = mk;
        ldelta[o] = dpack;
    }
}

// pass B: per row, flag subchunks whose lower-bound min <= rowmin + DELTA
__global__ void vq_flag(const u64* __restrict__ lmin, const uint32_t* __restrict__ ldelta,
                        uint32_t* __restrict__ wl, uint32_t* __restrict__ cnt) {
    int row = blockIdx.x * blockDim.x + threadIdx.x;
    if (row >= NROWS) return;
    const u64* lm = &lmin[(size_t)row * NCHUNK];
    u64 m = ~0ull;
#pragma unroll
    for (int c = 0; c < NCHUNK; ++c) { u64 v = lm[c]; m = (v < m) ? v : m; }
    float thr = funmono((uint32_t)(m >> 32)) + DELTA;
#pragma unroll 4
    for (int c = 0; c < NCHUNK; ++c) {
        float cf = funmono((uint32_t)(lm[c] >> 32));
        uint32_t d = ldelta[(size_t)row * NCHUNK + c];
#pragma unroll
        for (int s = 0; s < 4; ++s) {
            float slb = fmaf(0.25f, (float)((d >> (8 * s)) & 255u), cf);
            if (slb <= thr) {
                uint32_t p = atomicAdd(cnt, 1u);
                if (p < WLCAP) wl[p] = ((uint32_t)row << 7) | ((uint32_t)c << 2) | (uint32_t)s;
            }
        }
    }
}

// pass C: exact fp32 rescore of flagged 64-k subchunks; lowest-k tie-break.
__global__ void __launch_bounds__(256)
vq_rescore(const float* __restrict__ x, const float* __restrict__ wt,
           const float* __restrict__ wsq,
           const uint32_t* __restrict__ wl, const uint32_t* __restrict__ cnt,
           u64* __restrict__ keys) {
    const int t = threadIdx.x, wv = t >> 6, lane = t & 63;
    const uint32_t n0 = *cnt;
    const uint32_t n = (n0 < (uint32_t)WLCAP) ? n0 : (uint32_t)WLCAP;
    const uint32_t nw = gridDim.x * 4;
    for (uint32_t idx = blockIdx.x * 4 + wv; idx < n; idx += nw) {
        uint32_t e = wl[idx];
        int row = (int)(e >> 7);
        int k = ((int)((e >> 2) & 31)) * 256 + ((int)(e & 3)) * 64 + lane;
        const float4* xp = (const float4*)(x + (size_t)row * DDIM);   // wave-uniform
        const float4* wr = (const float4*)(wt + (size_t)k * DDIM);
        float a0 = 0.f, a1 = 0.f, a2 = 0.f, a3 = 0.f;
#pragma unroll
        for (int i = 0; i < DDIM / 4; ++i) {
            float4 xv = xp[i], wv4 = wr[i];
            a0 = fmaf(xv.x, wv4.x, a0);
            a1 = fmaf(xv.y, wv4.y, a1);
            a2 = fmaf(xv.z, wv4.z, a2);
            a3 = fmaf(xv.w, wv4.w, a3);
        }
        float dot = (a0 + a1) + (a2 + a3);            // same order as round-1 (matched np)
        float sc  = fmaf(-2.f, dot, wsq[k]);
        u64 key = ((u64)fmono(sc) << 32) | (unsigned)k;
        u64 o;
        o = __shfl_xor(key, 1);  key = (o < key) ? o : key;
        o = __shfl_xor(key, 2);  key = (o < key) ? o : key;
        o = __shfl_xor(key, 4);  key = (o < key) ? o : key;
        o = __shfl_xor(key, 8);  key = (o < key) ? o : key;
        o = __shfl_xor(key, 16); key = (o < key) ? o : key;
        o = __shfl_xor(key, 32); key = (o < key) ? o : key;
        if (lane == 0) atomicMin(&keys[row], key);
    }
}

__global__ void vq_gather(const u64* __restrict__ keys,
                          const float* __restrict__ wt,
                          float* __restrict__ out) {
    int t = blockIdx.x * blockDim.x + threadIdx.x;
    if (t >= NROWS * DDIM) return;
    int row = t >> 6;
    int d   = t & 63;
    int k   = (int)(keys[row] & 0xFFFFFFFFull);
    out[t] = wt[(size_t)k * DDIM + d];
}

// ================= fallback (round-3 fp32 path, ws < 21.3 MB) =================

#define BR 128
#define BK 128
#define DPH 32
typedef float v2f __attribute__((ext_vector_type(2)));

__global__ void fb_prep(const float* __restrict__ w, float* __restrict__ wt,
                        float* __restrict__ wsq) {
    int k = blockIdx.x * blockDim.x + threadIdx.x;
    if (k >= KDIM) return;
    float s = 0.f;
#pragma unroll
    for (int d = 0; d < DDIM; ++d) {
        float v = w[(size_t)d * KDIM + k];
        wt[(size_t)k * DDIM + d] = v;
        s = fmaf(v, v, s);
    }
    wsq[k] = s;
}
__global__ void fb_init(u64* __restrict__ keys) {
    int i = blockIdx.x * blockDim.x + threadIdx.x;
    if (i < NROWS) keys[i] = ~0ull;
}
__global__ void __launch_bounds__(256, 4)
fb_gemm(const float* __restrict__ x, const float* __restrict__ w,
        const float* __restrict__ wsq, u64* __restrict__ keys) {
    __shared__ float xT[DPH][BR];
    __shared__ float wl[DPH][BK];
    const int kblk  = blockIdx.x & (KDIM / BK - 1);
    const int rbase = (blockIdx.x >> 6) * BR;
    const int kbase = kblk * BK;
    const int t     = threadIdx.x;
    const int wave = t >> 6, lane = t & 63;
    const int rg = lane >> 3, cg = lane & 7;
    const int xoff = (wave >> 1) * 64 + rg * 8;
    const int coff = (wave & 1) * 64 + cg * 8;
    v2f acc[8][4];
#pragma unroll
    for (int i = 0; i < 8; ++i)
#pragma unroll
        for (int j = 0; j < 4; ++j) acc[i][j] = (v2f)(0.f);
#pragma unroll
    for (int p = 0; p < 2; ++p) {
        {
            const int row = t & 127, dgrp = t >> 7;
#pragma unroll
            for (int it = 0; it < 4; ++it) {
                const int dl = (dgrp + it * 2) * 4;
                float4 v = *(const float4*)&x[(size_t)(rbase + row) * DDIM + p * DPH + dl];
                xT[dl + 0][row] = v.x; xT[dl + 1][row] = v.y;
                xT[dl + 2][row] = v.z; xT[dl + 3][row] = v.w;
            }
        }
        {
#pragma unroll
            for (int it = 0; it < 4; ++it) {
                const int o4 = t + it * 256;
                const int dl = o4 >> 5, c4 = (o4 & 31) << 2;
                float4 v = *(const float4*)&w[(size_t)(p * DPH + dl) * KDIM + kbase + c4];
                *(float4*)&wl[dl][c4] = v;
            }
        }
        __syncthreads();
#pragma unroll 4
        for (int d = 0; d < DPH; ++d) {
            float4 xa = *(const float4*)&xT[d][xoff];
            float4 xb = *(const float4*)&xT[d][xoff + 4];
            float4 wa = *(const float4*)&wl[d][coff];
            float4 wb = *(const float4*)&wl[d][coff + 4];
            v2f wv0 = {wa.x, wa.y}, wv1 = {wa.z, wa.w};
            v2f wv2 = {wb.x, wb.y}, wv3 = {wb.z, wb.w};
            float xr[8] = {xa.x, xa.y, xa.z, xa.w, xb.x, xb.y, xb.z, xb.w};
#pragma unroll
            for (int i = 0; i < 8; ++i) {
                v2f xs = {xr[i], xr[i]};
                acc[i][0] = __builtin_elementwise_fma(xs, wv0, acc[i][0]);
                acc[i][1] = __builtin_elementwise_fma(xs, wv1, acc[i][1]);
                acc[i][2] = __builtin_elementwise_fma(xs, wv2, acc[i][2]);
                acc[i][3] = __builtin_elementwise_fma(xs, wv3, acc[i][3]);
            }
        }
        __syncthreads();
    }
    const int kc = kbase + coff;
    float4 qa = *(const float4*)&wsq[kc];
    float4 qb = *(const float4*)&wsq[kc + 4];
    v2f q2[4] = {{qa.x, qa.y}, {qa.z, qa.w}, {qb.x, qb.y}, {qb.z, qb.w}};
    const v2f neg2 = {-2.f, -2.f};
#pragma unroll
    for (int i = 0; i < 8; ++i) {
        float sc[8];
#pragma unroll
        for (int jj = 0; jj < 4; ++jj) {
            v2f s2 = __builtin_elementwise_fma(neg2, acc[i][jj], q2[jj]);
            sc[2 * jj] = s2.x; sc[2 * jj + 1] = s2.y;
        }
        float best = sc[0]; int bj = 0;
#pragma unroll
        for (int j = 1; j < 8; ++j)
            if (sc[j] < best) { best = sc[j]; bj = j; }
        u64 key = ((u64)fmono(best) << 32) | (unsigned)(kc + bj);
        u64 o;
        o = __shfl_xor(key, 1); key = (o < key) ? o : key;
        o = __shfl_xor(key, 2); key = (o < key) ? o : key;
        o = __shfl_xor(key, 4); key = (o < key) ? o : key;
        if (cg == 0) atomicMin(&keys[rbase + xoff + i], key);
    }
}

// ================= launch =================

extern "C" void kernel_launch(void* const* d_in, const int* in_sizes, int n_in,
                              void* d_out, int out_size, void* d_ws, size_t ws_size,
                              hipStream_t stream) {
    const float* x = (const float*)d_in[0];   // [32768, 64]
    const float* w = (const float*)d_in[1];   // [64, 8192]
    float* out = (float*)d_out;

    char* ws = (char*)d_ws;
    const size_t OFF_WT     = 0;
    const size_t OFF_WSQ    = 2097152;
    const size_t OFF_WTB    = 2129920;
    const size_t OFF_XB     = 3178496;
    const size_t OFF_LMIN   = 7372800;
    const size_t OFF_LDELTA = 15761408;
    const size_t OFF_KEYS   = 19955712;
    const size_t OFF_WL     = 20217856;
    const size_t OFF_CNT    = 21266432;
    const size_t NEED       = 21266448;

    if (ws_size >= NEED) {
        float*    wt     = (float*)(ws + OFF_WT);
        float*    wsq    = (float*)(ws + OFF_WSQ);
        ushort*   wtb    = (ushort*)(ws + OFF_WTB);
        ushort*   xbb    = (ushort*)(ws + OFF_XB);
        u64*      lmin   = (u64*)(ws + OFF_LMIN);
        uint32_t* ldelta = (uint32_t*)(ws + OFF_LDELTA);
        u64*      keys   = (u64*)(ws + OFF_KEYS);
        uint32_t* wl     = (uint32_t*)(ws + OFF_WL);
        uint32_t* cnt    = (uint32_t*)(ws + OFF_CNT);

        vq_prep_w<<<KDIM / 256, 256, 0, stream>>>(w, wt, wtb, wsq);
        vq_prep_x<<<(NROWS * DDIM / 4) / 256, 256, 0, stream>>>(x, xbb);
        vq_init2<<<NROWS / 256, 256, 0, stream>>>(keys, cnt);
        vq_scoreA<<<(NROWS / 64) * NCHUNK, 256, 0, stream>>>(xbb, wtb, wsq, lmin, ldelta);
        vq_flag<<<NROWS / 256, 256, 0, stream>>>(lmin, ldelta, wl, cnt);
        vq_rescore<<<1024, 256, 0, stream>>>(x, wt, wsq, wl, cnt, keys);
        vq_gather<<<(NROWS * DDIM) / 256, 256, 0, stream>>>(keys, wt, out);
    } else {
        float* wt  = (float*)ws;
        float* wsq = (float*)(ws + 2097152);
        u64*   keys = (u64*)(ws + 2129920);
        fb_prep<<<KDIM / 256, 256, 0, stream>>>(w, wt, wsq);
        fb_init<<<NROWS / 256, 256, 0, stream>>>(keys);
        fb_gemm<<<(NROWS / BR) * (KDIM / BK), 256, 0, stream>>>(x, w, wsq, keys);
        vq_gather<<<(NROWS * DDIM) / 256, 256, 0, stream>>>(keys, wt, out);
    }
}

// Round 5
// 297.956 us; speedup vs baseline: 2.2271x; 2.2271x over previous
//
#include <hip/hip_runtime.h>
#include <hip/hip_bf16.h>
#include <cstdint>
#include <cstddef>

#define NROWS 32768
#define DDIM  64
#define KDIM  8192
#define NSUB  128                 // 64-k subchunks per row
#define DELTA 3.0f                // covers 2*eps_bf16score + 2*bf16_ulp(storage)

typedef float  f32x4 __attribute__((ext_vector_type(4)));
typedef short  s16x8 __attribute__((ext_vector_type(8)));
typedef unsigned long long u64;

__device__ __forceinline__ uint32_t fmono(float f) {
    uint32_t u = __float_as_uint(f);
    return (u & 0x80000000u) ? ~u : (u | 0x80000000u);
}
__device__ __forceinline__ float bf2f(ushort s) {
    uint32_t u = (uint32_t)s << 16;
    return __uint_as_float(u);
}

// ================= fast path =================

// prep: LDS-tiled transpose w[d][k] -> wtb[k][d] (bf16), wsq[k] (serial fmaf order)
__global__ void __launch_bounds__(256)
vq_prep_w(const float* __restrict__ w, ushort* __restrict__ wtb,
          float* __restrict__ wsq) {
    __shared__ float tile[64][65];
    const int kbase = blockIdx.x * 64;
    const int t = threadIdx.x, wv = t >> 6, lane = t & 63;
#pragma unroll
    for (int it = 0; it < 16; ++it) {
        int d = it * 4 + wv;
        tile[lane][d] = w[(size_t)d * KDIM + kbase + lane];   // coalesced
    }
    __syncthreads();
#pragma unroll
    for (int it = 0; it < 16; ++it) {
        int kk = it * 4 + wv;
        float v = tile[kk][lane];                             // lane = d
        __hip_bfloat16 hb = __float2bfloat16(v);
        wtb[(size_t)(kbase + kk) * DDIM + lane] = *(ushort*)&hb;  // coalesced
    }
    if (wv == 0) {   // lane = k within tile; serial ascending-d fmaf (matches prior rounds)
        float s = 0.f;
#pragma unroll
        for (int d = 0; d < DDIM; ++d) {
            float v = tile[lane][d];
            s = fmaf(v, v, s);
        }
        wsq[kbase + lane] = s;
    }
}

// prep: x -> bf16
__global__ void vq_prep_x(const float* __restrict__ x, ushort* __restrict__ xb) {
    int i = blockIdx.x * blockDim.x + threadIdx.x;   // one float4 per thread
    if (i >= NROWS * DDIM / 4) return;
    float4 v = ((const float4*)x)[i];
    ushort4 o;
    __hip_bfloat16 h;
    h = __float2bfloat16(v.x); o.x = *(ushort*)&h;
    h = __float2bfloat16(v.y); o.y = *(ushort*)&h;
    h = __float2bfloat16(v.z); o.z = *(ushort*)&h;
    h = __float2bfloat16(v.w); o.w = *(ushort*)&h;
    ((ushort4*)xb)[i] = o;
}

// pass A: bf16 MFMA scores -> per-(row, 64k-subchunk) min (bf16), no argmin carried.
// Block: 64 rows x 256 k; wave wv owns subchunk kw..kw+63. 4x4 frags of 16x16x32.
__global__ void __launch_bounds__(256)
vq_scoreA(const ushort* __restrict__ xb, const ushort* __restrict__ wb,
          const float* __restrict__ wsq, ushort* __restrict__ lsub) {
    const int cidx  = blockIdx.x & 31;
    const int rbase = (blockIdx.x >> 5) * 64;
    const int t = threadIdx.x, wv = t >> 6, lane = t & 63;
    const int l15 = lane & 15, l4 = lane >> 4;
    const int kw = cidx * 256 + wv * 64;

    s16x8 bfrag[4][2];
#pragma unroll
    for (int ct = 0; ct < 4; ++ct)
#pragma unroll
        for (int h = 0; h < 2; ++h)
            bfrag[ct][h] = *(const s16x8*)&wb[(size_t)(kw + ct * 16 + l15) * DDIM + h * 32 + l4 * 8];

    f32x4 acc[4][4];
#pragma unroll
    for (int rt = 0; rt < 4; ++rt)
#pragma unroll
        for (int ct = 0; ct < 4; ++ct) acc[rt][ct] = (f32x4)(0.f);

#pragma unroll
    for (int rt = 0; rt < 4; ++rt) {
        const size_t rb = (size_t)(rbase + rt * 16 + l15) * DDIM + l4 * 8;
        s16x8 a0 = *(const s16x8*)&xb[rb];
        s16x8 a1 = *(const s16x8*)&xb[rb + 32];
#pragma unroll
        for (int ct = 0; ct < 4; ++ct) {
            acc[rt][ct] = __builtin_amdgcn_mfma_f32_16x16x32_bf16(a0, bfrag[ct][0], acc[rt][ct], 0, 0, 0);
            acc[rt][ct] = __builtin_amdgcn_mfma_f32_16x16x32_bf16(a1, bfrag[ct][1], acc[rt][ct], 0, 0, 0);
        }
    }

    float wq[4];
#pragma unroll
    for (int ct = 0; ct < 4; ++ct) wq[ct] = wsq[kw + ct * 16 + l15];

    // C/D layout (verified r4): col k = lane&15 (via wq), row = (lane>>4)*4 + reg
#pragma unroll
    for (int rt = 0; rt < 4; ++rt) {
#pragma unroll
        for (int i = 0; i < 4; ++i) {
            float m = fmaf(-2.f, acc[rt][0][i], wq[0]);
            m = fminf(m, fmaf(-2.f, acc[rt][1][i], wq[1]));
            m = fminf(m, fmaf(-2.f, acc[rt][2][i], wq[2]));
            m = fminf(m, fmaf(-2.f, acc[rt][3][i], wq[3]));
            m = fminf(m, __shfl_xor(m, 1));
            m = fminf(m, __shfl_xor(m, 2));
            m = fminf(m, __shfl_xor(m, 4));
            m = fminf(m, __shfl_xor(m, 8));
            if (l15 == 0) {
                __hip_bfloat16 hb = __float2bfloat16(m);
                lsub[(size_t)(rbase + rt * 16 + l4 * 4 + i) * NSUB + cidx * 4 + wv] = *(ushort*)&hb;
            }
        }
    }
}

// finish: per-row (one wave): threshold -> ballot flags -> exact fp32 rescore of
// flagged subchunks -> fused gather. No atomics, no worklist.
__global__ void __launch_bounds__(256)
vq_finish(const float* __restrict__ x, const float* __restrict__ w,
          const float* __restrict__ wsq, const ushort* __restrict__ lsub,
          float* __restrict__ out) {
    const int wv = threadIdx.x >> 6, lane = threadIdx.x & 63;
    const int row = blockIdx.x * 4 + wv;

    ushort2 us = *(const ushort2*)&lsub[(size_t)row * NSUB + lane * 2];   // coalesced
    float v0 = bf2f(us.x), v1 = bf2f(us.y);
    float m = fminf(v0, v1);
#pragma unroll
    for (int o = 1; o < 64; o <<= 1) m = fminf(m, __shfl_xor(m, o));
    const float thr = m + DELTA;
    u64 b0 = __ballot(v0 <= thr);   // bit s -> subchunk 2s
    u64 b1 = __ballot(v1 <= thr);   // bit s -> subchunk 2s+1

    float4 xr[16];
    const float4* xp = (const float4*)(x + (size_t)row * DDIM);
#pragma unroll
    for (int i = 0; i < 16; ++i) xr[i] = xp[i];   // wave-uniform row

    u64 best = ~0ull;
#pragma unroll
    for (int half = 0; half < 2; ++half) {
        u64 b = half ? b1 : b0;
        while (b) {                      // wave-uniform loop (ballot masks identical)
            int s = __ffsll(b) - 1;
            b &= b - 1;
            int kk = (s * 2 + half) * 64 + lane;
            float a0 = 0.f, a1 = 0.f, a2 = 0.f, a3 = 0.f;
#pragma unroll
            for (int i = 0; i < 16; ++i) {
                a0 = fmaf(xr[i].x, w[(size_t)(4 * i + 0) * KDIM + kk], a0);
                a1 = fmaf(xr[i].y, w[(size_t)(4 * i + 1) * KDIM + kk], a1);
                a2 = fmaf(xr[i].z, w[(size_t)(4 * i + 2) * KDIM + kk], a2);
                a3 = fmaf(xr[i].w, w[(size_t)(4 * i + 3) * KDIM + kk], a3);
            }
            float dot = (a0 + a1) + (a2 + a3);       // same order as round-1 (matched np)
            float sc  = fmaf(-2.f, dot, wsq[kk]);
            u64 key = ((u64)fmono(sc) << 32) | (unsigned)kk;
#pragma unroll
            for (int sh = 1; sh < 64; sh <<= 1) {
                u64 o = __shfl_xor(key, sh);
                key = (o < key) ? o : key;
            }
            best = (key < best) ? key : best;        // lowest-k tie-break preserved
        }
    }
    const int bestk = (int)(best & 0xFFFFFFFFull);
    out[(size_t)row * DDIM + lane] = w[(size_t)lane * KDIM + bestk];  // fused gather
}

// ================= fallback (round-3 fp32 path, small ws) =================

#define BR 128
#define BK 128
#define DPH 32
typedef float v2f __attribute__((ext_vector_type(2)));

__global__ void fb_prep(const float* __restrict__ w, float* __restrict__ wt,
                        float* __restrict__ wsq) {
    int k = blockIdx.x * blockDim.x + threadIdx.x;
    if (k >= KDIM) return;
    float s = 0.f;
#pragma unroll
    for (int d = 0; d < DDIM; ++d) {
        float v = w[(size_t)d * KDIM + k];
        wt[(size_t)k * DDIM + d] = v;
        s = fmaf(v, v, s);
    }
    wsq[k] = s;
}
__global__ void fb_init(u64* __restrict__ keys) {
    int i = blockIdx.x * blockDim.x + threadIdx.x;
    if (i < NROWS) keys[i] = ~0ull;
}
__global__ void __launch_bounds__(256, 4)
fb_gemm(const float* __restrict__ x, const float* __restrict__ w,
        const float* __restrict__ wsq, u64* __restrict__ keys) {
    __shared__ float xT[DPH][BR];
    __shared__ float wl[DPH][BK];
    const int kblk  = blockIdx.x & (KDIM / BK - 1);
    const int rbase = (blockIdx.x >> 6) * BR;
    const int kbase = kblk * BK;
    const int t     = threadIdx.x;
    const int wave = t >> 6, lane = t & 63;
    const int rg = lane >> 3, cg = lane & 7;
    const int xoff = (wave >> 1) * 64 + rg * 8;
    const int coff = (wave & 1) * 64 + cg * 8;
    v2f acc[8][4];
#pragma unroll
    for (int i = 0; i < 8; ++i)
#pragma unroll
        for (int j = 0; j < 4; ++j) acc[i][j] = (v2f)(0.f);
#pragma unroll
    for (int p = 0; p < 2; ++p) {
        {
            const int row = t & 127, dgrp = t >> 7;
#pragma unroll
            for (int it = 0; it < 4; ++it) {
                const int dl = (dgrp + it * 2) * 4;
                float4 v = *(const float4*)&x[(size_t)(rbase + row) * DDIM + p * DPH + dl];
                xT[dl + 0][row] = v.x; xT[dl + 1][row] = v.y;
                xT[dl + 2][row] = v.z; xT[dl + 3][row] = v.w;
            }
        }
        {
#pragma unroll
            for (int it = 0; it < 4; ++it) {
                const int o4 = t + it * 256;
                const int dl = o4 >> 5, c4 = (o4 & 31) << 2;
                float4 v = *(const float4*)&w[(size_t)(p * DPH + dl) * KDIM + kbase + c4];
                *(float4*)&wl[dl][c4] = v;
            }
        }
        __syncthreads();
#pragma unroll 4
        for (int d = 0; d < DPH; ++d) {
            float4 xa = *(const float4*)&xT[d][xoff];
            float4 xb = *(const float4*)&xT[d][xoff + 4];
            float4 wa = *(const float4*)&wl[d][coff];
            float4 wb = *(const float4*)&wl[d][coff + 4];
            v2f wv0 = {wa.x, wa.y}, wv1 = {wa.z, wa.w};
            v2f wv2 = {wb.x, wb.y}, wv3 = {wb.z, wb.w};
            float xrr[8] = {xa.x, xa.y, xa.z, xa.w, xb.x, xb.y, xb.z, xb.w};
#pragma unroll
            for (int i = 0; i < 8; ++i) {
                v2f xs = {xrr[i], xrr[i]};
                acc[i][0] = __builtin_elementwise_fma(xs, wv0, acc[i][0]);
                acc[i][1] = __builtin_elementwise_fma(xs, wv1, acc[i][1]);
                acc[i][2] = __builtin_elementwise_fma(xs, wv2, acc[i][2]);
                acc[i][3] = __builtin_elementwise_fma(xs, wv3, acc[i][3]);
            }
        }
        __syncthreads();
    }
    const int kc = kbase + coff;
    float4 qa = *(const float4*)&wsq[kc];
    float4 qb = *(const float4*)&wsq[kc + 4];
    v2f q2[4] = {{qa.x, qa.y}, {qa.z, qa.w}, {qb.x, qb.y}, {qb.z, qb.w}};
    const v2f neg2 = {-2.f, -2.f};
#pragma unroll
    for (int i = 0; i < 8; ++i) {
        float sc[8];
#pragma unroll
        for (int jj = 0; jj < 4; ++jj) {
            v2f s2 = __builtin_elementwise_fma(neg2, acc[i][jj], q2[jj]);
            sc[2 * jj] = s2.x; sc[2 * jj + 1] = s2.y;
        }
        float bestv = sc[0]; int bj = 0;
#pragma unroll
        for (int j = 1; j < 8; ++j)
            if (sc[j] < bestv) { bestv = sc[j]; bj = j; }
        u64 key = ((u64)fmono(bestv) << 32) | (unsigned)(kc + bj);
        u64 o;
        o = __shfl_xor(key, 1); key = (o < key) ? o : key;
        o = __shfl_xor(key, 2); key = (o < key) ? o : key;
        o = __shfl_xor(key, 4); key = (o < key) ? o : key;
        if (cg == 0) atomicMin(&keys[rbase + xoff + i], key);
    }
}
__global__ void fb_gather(const u64* __restrict__ keys,
                          const float* __restrict__ wt,
                          float* __restrict__ out) {
    int t = blockIdx.x * blockDim.x + threadIdx.x;
    if (t >= NROWS * DDIM) return;
    int row = t >> 6;
    int d   = t & 63;
    int k   = (int)(keys[row] & 0xFFFFFFFFull);
    out[t] = wt[(size_t)k * DDIM + d];
}

// ================= launch =================

extern "C" void kernel_launch(void* const* d_in, const int* in_sizes, int n_in,
                              void* d_out, int out_size, void* d_ws, size_t ws_size,
                              hipStream_t stream) {
    const float* x = (const float*)d_in[0];   // [32768, 64]
    const float* w = (const float*)d_in[1];   // [64, 8192]
    float* out = (float*)d_out;

    char* ws = (char*)d_ws;
    const size_t OFF_WTB  = 0;               // 8192*64*2  = 1 MiB
    const size_t OFF_WSQ  = 1048576;         // 32 KiB
    const size_t OFF_XB   = 1081344;         // 32768*64*2 = 4 MiB
    const size_t OFF_LSUB = 5275648;         // 32768*128*2 = 8 MiB
    const size_t NEED     = 13664256;

    if (ws_size >= NEED) {
        ushort* wtb  = (ushort*)(ws + OFF_WTB);
        float*  wsq  = (float*)(ws + OFF_WSQ);
        ushort* xbb  = (ushort*)(ws + OFF_XB);
        ushort* lsub = (ushort*)(ws + OFF_LSUB);

        vq_prep_w<<<KDIM / 64, 256, 0, stream>>>(w, wtb, wsq);
        vq_prep_x<<<(NROWS * DDIM / 4) / 256, 256, 0, stream>>>(x, xbb);
        vq_scoreA<<<(NROWS / 64) * 32, 256, 0, stream>>>(xbb, wtb, wsq, lsub);
        vq_finish<<<NROWS / 4, 256, 0, stream>>>(x, w, wsq, lsub, out);
    } else {
        float* wt  = (float*)ws;
        float* wsq = (float*)(ws + 2097152);
        u64*   keys = (u64*)(ws + 2129920);
        fb_prep<<<KDIM / 256, 256, 0, stream>>>(w, wt, wsq);
        fb_init<<<NROWS / 256, 256, 0, stream>>>(keys);
        fb_gemm<<<(NROWS / BR) * (KDIM / BK), 256, 0, stream>>>(x, w, wsq, keys);
        fb_gather<<<(NROWS * DDIM) / 256, 256, 0, stream>>>(keys, wt, out);
    }
}